// Round 2
// baseline (207.831 us; speedup 1.0000x reference)
//
#include <hip/hip_runtime.h>
#include <math.h>

#define BB 4
#define SQL 512
#define SKL 512
#define HH 256
#define AA 128

// 2 * log2(e): Qt/Kt pre-scaled so score loop feeds v_exp_f32 (2^x) directly.
#define PRESCALE 2.8853900817779268f

__device__ inline void fma4(float4& a, float s, const float4& b) {
    a.x = fmaf(s, b.x, a.x); a.y = fmaf(s, b.y, a.y);
    a.z = fmaf(s, b.z, a.z); a.w = fmaf(s, b.w, a.w);
}

// ---------------------------------------------------------------------------
// Kernel 1 "prep": Qt = PRESCALE*(Q@W_q), Kt = PRESCALE*(K@W_k), VW = V@W_o.
// grid 1024 x 128 thr. blocks [0,256): Qt; [256,512): Kt; [512,768): VW cols
// 0..127; [768,1024): VW cols 128..255. Each block: 8 rows x 128 cols.
// ---------------------------------------------------------------------------
__global__ __launch_bounds__(128) void prep_kernel(
    const float* __restrict__ Q, const float* __restrict__ K,
    const float* __restrict__ V,
    const float* __restrict__ Wq, const float* __restrict__ Wk,
    const float* __restrict__ Wo,
    float* __restrict__ Qt, float* __restrict__ Kt, float* __restrict__ VW)
{
    __shared__ float rows[8][HH];   // 8 KB
    int bid = blockIdx.x;
    int tid = threadIdx.x;
    int t  = bid >> 8;              // 0:Qt 1:Kt 2:VW-lo 3:VW-hi
    int r0 = (bid & 255) * 8;

    const float* X; const float* W; float* Y; int ldW, ldY, col0; float scale;
    if (t == 0)      { X = Q; W = Wq; Y = Qt; ldW = AA; ldY = AA; col0 = 0;   scale = PRESCALE; }
    else if (t == 1) { X = K; W = Wk; Y = Kt; ldW = AA; ldY = AA; col0 = 0;   scale = PRESCALE; }
    else             { X = V; W = Wo; Y = VW; ldW = HH; ldY = HH; col0 = (t == 3) ? 128 : 0; scale = 1.0f; }

    // stage 8 input rows (2048 floats) via float4, coalesced
    {
        const float4* Xv = (const float4*)(X + (size_t)r0 * HH);
        float4* rv = (float4*)&rows[0][0];
        for (int i = tid; i < 8 * HH / 4; i += 128) rv[i] = Xv[i];
    }
    __syncthreads();

    float acc[8] = {0.f,0.f,0.f,0.f,0.f,0.f,0.f,0.f};
    const float* Wp = W + col0 + tid;
    #pragma unroll 4
    for (int h = 0; h < HH; ++h) {
        float w = Wp[(size_t)h * ldW];       // coalesced, L2-hot
        #pragma unroll
        for (int r = 0; r < 8; ++r) acc[r] = fmaf(rows[r][h], w, acc[r]);
    }
    #pragma unroll
    for (int r = 0; r < 8; ++r)
        Y[(size_t)(r0 + r) * ldY + col0 + tid] = scale * acc[r];
}

// ---------------------------------------------------------------------------
// Kernel 2: fused scores + softmax + (weights @ VW + b_o).
// grid = B*SQ/4 = 512 blocks, 256 threads. Block = (batch, 4 q-rows).
//   score[q][k] = S_all - sum_a 2*v[a] * rcp(2^(Qt[q][a]+Kt[k][a]) + 1)
//   (Qt/Kt carry the 2*log2e prescale; no clamp needed: exp->inf => rcp->0,
//    exp->0 => rcp(1)=1 — exactly the tanh limits.)
// Epilogue: wave qi owns q-row qi, lane owns 4 h-cols; VW read direct from
// global (L2-hot), weights broadcast from LDS.
// ---------------------------------------------------------------------------
__global__ __launch_bounds__(256) void score_kernel(
    const float* __restrict__ Qt, const float* __restrict__ Kt,
    const float* __restrict__ v,  const float* __restrict__ VW,
    const float* __restrict__ bo,
    float* __restrict__ weights,  float* __restrict__ out)
{
    __shared__ float kt_lds[64 * 129];   // 33 KB, stride 129 -> (k+a)%32 banks
    __shared__ float qrow[4][AA];        // 2 KB
    __shared__ float vv[AA];             // 0.5 KB
    __shared__ float score[4][SKL];      // 8 KB
    __shared__ float part[16][64];       // 4 KB  [qi*4+ag][k_local]

    int tid = threadIdx.x;
    int b  = blockIdx.x >> 7;            // 128 blocks per batch
    int q0 = (blockIdx.x & 127) << 2;

    {
        const float4* Qv = (const float4*)(Qt + (size_t)(b * SQL + q0) * AA);
        float4* qv = (float4*)&qrow[0][0];
        for (int i = tid; i < 4 * AA / 4; i += 256) qv[i] = Qv[i];
        if (tid < AA) vv[tid] = v[tid];
    }
    __syncthreads();

    int k_local = tid & 63;
    int ag      = tid >> 6;              // a in [ag*32, ag*32+32)

    float S_all = 0.f;
    #pragma unroll
    for (int j = 0; j < AA; ++j) S_all += vv[j];

    for (int c = 0; c < 8; ++c) {
        int k0 = c * 64;
        // stage 64 Kt rows: float4 global reads, scalar LDS writes (pad 129)
        {
            const float4* Kv = (const float4*)(Kt + (size_t)(b * SKL + k0) * AA);
            for (int i = tid; i < 64 * AA / 4; i += 256) {
                int r = i >> 5, c4 = (i & 31) << 2;
                float4 val = Kv[i];
                float* dst = &kt_lds[r * 129 + c4];
                dst[0] = val.x; dst[1] = val.y; dst[2] = val.z; dst[3] = val.w;
            }
        }
        __syncthreads();

        float p[4] = {0.f,0.f,0.f,0.f};
        int base = k_local * 129 + ag * 32;
        #pragma unroll 8
        for (int j = 0; j < 32; ++j) {
            int a = ag * 32 + j;
            float kv = kt_lds[base + j];       // conflict-free
            float va = vv[a];                  // broadcast
            float v2 = va + va;
            #pragma unroll
            for (int qi = 0; qi < 4; ++qi) {
                float x = qrow[qi][a] + kv;    // = 2*log2e*(Qt+Kt)
                float t = __builtin_amdgcn_exp2f(x);
                float r = __builtin_amdgcn_rcpf(t + 1.0f);
                p[qi] = fmaf(v2, r, p[qi]);
            }
        }
        #pragma unroll
        for (int qi = 0; qi < 4; ++qi)
            part[qi * 4 + ag][k_local] = p[qi];
        __syncthreads();

        {   // reduce 4 a-groups: 256 threads cover 4q x 64k
            int qi = tid >> 6, kk = tid & 63;
            score[qi][k0 + kk] = S_all -
                (part[qi * 4 + 0][kk] + part[qi * 4 + 1][kk] +
                 part[qi * 4 + 2][kk] + part[qi * 4 + 3][kk]);
        }
        // safe without extra sync: next kt staging only happens after all
        // threads passed the post-part sync; part rewritten after next sync.
    }
    __syncthreads();

    // ---- softmax: wave qi handles q-row qi; leaves NORMALIZED weights in LDS
    int qi = tid >> 6, lane = tid & 63;
    {
        float m = -1e30f;
        for (int k = lane; k < SKL; k += 64) m = fmaxf(m, score[qi][k]);
        #pragma unroll
        for (int off = 32; off; off >>= 1) m = fmaxf(m, __shfl_xor(m, off));
        float s = 0.f;
        for (int k = lane; k < SKL; k += 64) {
            float e = __builtin_amdgcn_exp2f((score[qi][k] - m) * 1.44269504f);
            score[qi][k] = e;
            s += e;
        }
        #pragma unroll
        for (int off = 32; off; off >>= 1) s += __shfl_xor(s, off);
        float rinv = 1.0f / s;
        size_t rowoff = (size_t)(b * SQL + q0 + qi) * SKL;
        for (int k = lane; k < SKL; k += 64) {
            float wv = score[qi][k] * rinv;
            score[qi][k] = wv;                 // reused by epilogue (same wave)
            weights[rowoff + k] = wv;
        }
    }

    // ---- epilogue: out[q0+qi][:] = weights-row @ VW + b_o
    // wave qi owns its own score row (no cross-wave dep -> no sync needed).
    {
        const float4* VWv = (const float4*)(VW + (size_t)b * SKL * HH);
        float4 acc4 = ((const float4*)bo)[lane];
        #pragma unroll 2
        for (int k = 0; k < SKL; k += 4) {
            float4 w4 = *(const float4*)&score[qi][k];   // broadcast b128
            float4 a0 = VWv[(k + 0) * (HH / 4) + lane];  // coalesced dwordx4
            float4 a1 = VWv[(k + 1) * (HH / 4) + lane];
            float4 a2 = VWv[(k + 2) * (HH / 4) + lane];
            float4 a3 = VWv[(k + 3) * (HH / 4) + lane];
            fma4(acc4, w4.x, a0);
            fma4(acc4, w4.y, a1);
            fma4(acc4, w4.z, a2);
            fma4(acc4, w4.w, a3);
        }
        float* op = out + (size_t)(b * SQL + q0 + qi) * HH + 4 * lane;
        *(float4*)op = acc4;
    }
}

// ---------------------------------------------------------------------------
extern "C" void kernel_launch(void* const* d_in, const int* in_sizes, int n_in,
                              void* d_out, int out_size, void* d_ws, size_t ws_size,
                              hipStream_t stream)
{
    const float* Q  = (const float*)d_in[0];
    const float* K  = (const float*)d_in[1];
    const float* V  = (const float*)d_in[2];
    const float* Wq = (const float*)d_in[3];
    const float* Wk = (const float*)d_in[4];
    const float* v  = (const float*)d_in[5];
    const float* Wo = (const float*)d_in[6];
    const float* bo = (const float*)d_in[7];

    float* out     = (float*)d_out;                       // (B,SQ,H) = 524288
    float* weights = out + (size_t)BB * SQL * HH;         // (B,SQ,SK) = 1048576

    float* Qt = (float*)d_ws;                             // 262144 floats
    float* Kt = Qt + (size_t)BB * SQL * AA;               // 262144 floats
    float* VW = Kt + (size_t)BB * SKL * AA;               // 524288 floats

    prep_kernel <<<1024, 128, 0, stream>>>(Q, K, V, Wq, Wk, Wo, Qt, Kt, VW);
    score_kernel<<<512, 256, 0, stream>>>(Qt, Kt, v, VW, bo, weights, out);
}

// Round 3
// 137.503 us; speedup vs baseline: 1.5115x; 1.5115x over previous
//
#include <hip/hip_runtime.h>
#include <math.h>

#define BB 4
#define SQL 512
#define SKL 512
#define HH 256
#define AA 128

// 2 * log2(e): Qt/Kt pre-scaled so the score loop feeds v_exp_f32 (2^x) directly.
#define PRESCALE 2.8853900817779268f

__device__ inline void fma4(float4& a, float s, const float4& b) {
    a.x = fmaf(s, b.x, a.x); a.y = fmaf(s, b.y, a.y);
    a.z = fmaf(s, b.z, a.z); a.w = fmaf(s, b.w, a.w);
}

// ---------------------------------------------------------------------------
// Kernel 1 "prep": Qt = PRESCALE*(Q@W_q), Kt = PRESCALE*(K@W_k), VW = V@W_o.
// grid 1024 x 256 thr. Block = 8 output rows x 128 output cols.
//   [0,256): Qt   [256,512): Kt   [512,1024): VW (row-block, col-half)
// Both operands staged in LDS (float4), compute via ds_read_b128 only —
// NO per-iteration global loads (the R2 latency killer).
// LDS = 8KB rows + 32KB W = 40KB -> 4 blocks/CU.
// ---------------------------------------------------------------------------
__global__ __launch_bounds__(256, 4) void prep_kernel(
    const float* __restrict__ Q, const float* __restrict__ K,
    const float* __restrict__ V,
    const float* __restrict__ Wq, const float* __restrict__ Wk,
    const float* __restrict__ Wo,
    float* __restrict__ Qt, float* __restrict__ Kt, float* __restrict__ VW)
{
    __shared__ float rows[8 * HH];     // 8 KB
    __shared__ float wl[64 * 128];     // 32 KB
    int tid = threadIdx.x;
    int bid = blockIdx.x;

    const float* X; const float* W; float* Y;
    int ldW, ldY, col0, r0; float scale;
    if (bid < 256)      { X=Q; W=Wq; Y=Qt; ldW=AA; ldY=AA; col0=0; r0=bid*8;        scale=PRESCALE; }
    else if (bid < 512) { X=K; W=Wk; Y=Kt; ldW=AA; ldY=AA; col0=0; r0=(bid-256)*8;  scale=PRESCALE; }
    else { int b2=bid-512; X=V; W=Wo; Y=VW; ldW=HH; ldY=HH; col0=(b2&1)*128; r0=(b2>>1)*8; scale=1.0f; }

    // stage 8 input rows (2048 floats, contiguous, float4)
    {
        const float4* Xv = (const float4*)(X + (size_t)r0 * HH);
        float4* rv = (float4*)rows;
        rv[tid]       = Xv[tid];
        rv[tid + 256] = Xv[tid + 256];
    }

    int r  = tid >> 5;       // 0..7  output row
    int c4 = tid & 31;       // float4 output col
    float4 acc = {0.f, 0.f, 0.f, 0.f};

    for (int ch = 0; ch < 4; ++ch) {
        __syncthreads();     // compute(ch-1) done / rows staged
        {   // stage W rows [ch*64, ch*64+64) x cols [col0,col0+128): 2048 float4
            const float* Wbase = W + (size_t)(ch * 64) * ldW + col0;
            float4* wv = (float4*)wl;
            #pragma unroll
            for (int it = 0; it < 8; ++it) {
                int l = tid + it * 256;
                wv[l] = *(const float4*)(Wbase + (size_t)(l >> 5) * ldW + ((l & 31) << 2));
            }
        }
        __syncthreads();
        const float* rrow = rows + r * HH + ch * 64;
        #pragma unroll 4
        for (int h4 = 0; h4 < 16; ++h4) {
            float4 rv = *(const float4*)(rrow + h4 * 4);        // broadcast b128
            const float* wbase = wl + (h4 * 4) * 128 + (c4 << 2);
            float4 w0 = *(const float4*)(wbase);                // contiguous b128
            float4 w1 = *(const float4*)(wbase + 128);
            float4 w2 = *(const float4*)(wbase + 256);
            float4 w3 = *(const float4*)(wbase + 384);
            fma4(acc, rv.x, w0); fma4(acc, rv.y, w1);
            fma4(acc, rv.z, w2); fma4(acc, rv.w, w3);
        }
    }
    acc.x *= scale; acc.y *= scale; acc.z *= scale; acc.w *= scale;
    *(float4*)(Y + (size_t)(r0 + r) * ldY + col0 + (c4 << 2)) = acc;
}

// ---------------------------------------------------------------------------
// Kernel 2: fused scores + softmax + (weights @ VW + b_o).
// grid = B*SQ/2 = 1024 blocks x 256 thr (4 blocks/CU, 16 waves/CU).
//   score[q][k] = S_all - sum_a 2*v[a] * rcp(2^(Qt[q][a]+Kt[k][a]) + 1)
// Thread = (k_local = tid&31, a-group = tid>>5 of 16 a's); Qt row fragment and
// 2*v fragment live in REGISTERS (no per-element qrow LDS reads).
// Kt chunk = 32 rows, LDS stride 129 -> (k+a)%32 banks, 2-way = free.
// Epilogue: wave w owns k-quarter; VW read ONCE per block; LDS tree-reduce.
// ---------------------------------------------------------------------------
__global__ __launch_bounds__(256, 4) void score_kernel(
    const float* __restrict__ Qt, const float* __restrict__ Kt,
    const float* __restrict__ v,  const float* __restrict__ VW,
    const float* __restrict__ bo,
    float* __restrict__ weights,  float* __restrict__ out)
{
    __shared__ float kt_lds[32 * 129];   // 16.5 KB
    __shared__ float score[2][SKL];      // 4 KB
    __shared__ float part[2][8][32];     // 2 KB
    __shared__ float pout[4][2][HH];     // 8 KB
    __shared__ float vv[AA];             // 0.5 KB   (total ~31 KB)

    int tid = threadIdx.x;
    int b  = blockIdx.x >> 8;            // 256 blocks per batch
    int q0 = (blockIdx.x & 255) << 1;    // 2 q-rows per block
    int kl = tid & 31;                   // k within 32-chunk
    int ag = tid >> 5;                   // a-range [ag*16, ag*16+16)

    if (tid < AA) vv[tid] = v[tid];

    // register caches: Qt fragments + 2*v fragment
    float qreg0[16], qreg1[16], v2reg[16];
    {
        const float* vp = v + ag * 16;
        const float* qp0 = Qt + (size_t)(b * SQL + q0)     * AA + ag * 16;
        const float* qp1 = Qt + (size_t)(b * SQL + q0 + 1) * AA + ag * 16;
        #pragma unroll
        for (int j = 0; j < 16; ++j) {
            v2reg[j] = 2.0f * vp[j];
            qreg0[j] = qp0[j];
            qreg1[j] = qp1[j];
        }
    }
    __syncthreads();
    float S_all = 0.f;
    #pragma unroll
    for (int a = 0; a < AA; ++a) S_all += vv[a];   // broadcast reads, once

    for (int c = 0; c < 16; ++c) {
        {   // stage Kt rows [c*32, c*32+32): float4 global, scalar LDS (pad 129)
            const float4* Kv = (const float4*)(Kt + (size_t)(b * SKL + c * 32) * AA);
            #pragma unroll
            for (int it = 0; it < 4; ++it) {
                int l = tid + it * 256;              // 1024 float4
                int rr = l >> 5, cc = (l & 31) << 2;
                float4 val = Kv[l];
                float* dst = kt_lds + rr * 129 + cc;
                dst[0] = val.x; dst[1] = val.y; dst[2] = val.z; dst[3] = val.w;
            }
        }
        __syncthreads();

        float p0 = 0.f, p1 = 0.f;
        const float* kp = kt_lds + kl * 129 + ag * 16;
        #pragma unroll
        for (int j = 0; j < 16; ++j) {
            float kv = kp[j];                         // 2-way bank = free
            float x0 = qreg0[j] + kv;
            float x1 = qreg1[j] + kv;
            float e0 = __builtin_amdgcn_exp2f(x0);
            float e1 = __builtin_amdgcn_exp2f(x1);
            float r0 = __builtin_amdgcn_rcpf(e0 + 1.0f);
            float r1 = __builtin_amdgcn_rcpf(e1 + 1.0f);
            p0 = fmaf(v2reg[j], r0, p0);
            p1 = fmaf(v2reg[j], r1, p1);
        }
        part[0][ag][kl] = p0;
        part[1][ag][kl] = p1;
        __syncthreads();                              // part ready; kt free

        if (tid < 64) {
            int qi = tid >> 5, kk = tid & 31;
            float s = 0.f;
            #pragma unroll
            for (int g = 0; g < 8; ++g) s += part[qi][g][kk];
            score[qi][c * 32 + kk] = S_all - s;
        }
        // next staging races nothing: kt reads done before barrier above;
        // part rewritten only after the next post-staging barrier.
    }
    __syncthreads();

    // ---- softmax: wave 0 -> row 0, wave 1 -> row 1
    int wave = tid >> 6, lane = tid & 63;
    if (wave < 2) {
        int qi = wave;
        float m = -1e30f;
        for (int k = lane; k < SKL; k += 64) m = fmaxf(m, score[qi][k]);
        #pragma unroll
        for (int off = 32; off; off >>= 1) m = fmaxf(m, __shfl_xor(m, off));
        float s = 0.f;
        for (int k = lane; k < SKL; k += 64) {
            float e = __builtin_amdgcn_exp2f((score[qi][k] - m) * 1.44269504f);
            score[qi][k] = e;
            s += e;
        }
        #pragma unroll
        for (int off = 32; off; off >>= 1) s += __shfl_xor(s, off);
        float rinv = 1.0f / s;
        size_t rowoff = (size_t)(b * SQL + q0 + qi) * SKL;
        for (int k = lane; k < SKL; k += 64) {
            float wv2 = score[qi][k] * rinv;
            score[qi][k] = wv2;
            weights[rowoff + k] = wv2;
        }
    }
    __syncthreads();

    // ---- epilogue: wave w owns k in [128w, 128w+128); one VW read serves both q
    {
        const float4* VWb = (const float4*)(VW + (size_t)b * SKL * HH);
        float4 a0 = {0,0,0,0}, a1 = {0,0,0,0};
        int kbase = wave * 128;
        #pragma unroll 4
        for (int k = 0; k < 128; ++k) {
            int kk = kbase + k;
            float4 vw4 = VWb[kk * (HH / 4) + lane];   // coalesced dwordx4
            float w0 = score[0][kk];                  // wave-uniform broadcast
            float w1 = score[1][kk];
            fma4(a0, w0, vw4);
            fma4(a1, w1, vw4);
        }
        *(float4*)&pout[wave][0][lane << 2] = a0;
        *(float4*)&pout[wave][1][lane << 2] = a1;
    }
    __syncthreads();
    {
        int h = tid;
        float bias = bo[h];
        #pragma unroll
        for (int qi = 0; qi < 2; ++qi) {
            float s = bias + pout[0][qi][h] + pout[1][qi][h]
                           + pout[2][qi][h] + pout[3][qi][h];
            out[(size_t)(b * SQL + q0 + qi) * HH + h] = s;
        }
    }
}

// ---------------------------------------------------------------------------
extern "C" void kernel_launch(void* const* d_in, const int* in_sizes, int n_in,
                              void* d_out, int out_size, void* d_ws, size_t ws_size,
                              hipStream_t stream)
{
    const float* Q  = (const float*)d_in[0];
    const float* K  = (const float*)d_in[1];
    const float* V  = (const float*)d_in[2];
    const float* Wq = (const float*)d_in[3];
    const float* Wk = (const float*)d_in[4];
    const float* v  = (const float*)d_in[5];
    const float* Wo = (const float*)d_in[6];
    const float* bo = (const float*)d_in[7];

    float* out     = (float*)d_out;                   // (B,SQ,H) = 524288
    float* weights = out + (size_t)BB * SQL * HH;     // (B,SQ,SK) = 1048576

    float* Qt = (float*)d_ws;                         // 262144 floats
    float* Kt = Qt + (size_t)BB * SQL * AA;           // 262144 floats
    float* VW = Kt + (size_t)BB * SKL * AA;           // 524288 floats

    prep_kernel <<<1024, 256, 0, stream>>>(Q, K, V, Wq, Wk, Wo, Qt, Kt, VW);
    score_kernel<<<1024, 256, 0, stream>>>(Qt, Kt, v, VW, bo, weights, out);
}

// Round 4
// 129.763 us; speedup vs baseline: 1.6016x; 1.0597x over previous
//
#include <hip/hip_runtime.h>
#include <math.h>

#define BB 4
#define SQL 512
#define SKL 512
#define HH 256
#define AA 128

// 2 * log2(e): Qt/Kt pre-scaled so the score loop feeds v_exp_f32 (2^x) directly.
#define PRESCALE 2.8853900817779268f

__device__ inline void fma4(float4& a, float s, const float4& b) {
    a.x = fmaf(s, b.x, a.x); a.y = fmaf(s, b.y, a.y);
    a.z = fmaf(s, b.z, a.z); a.w = fmaf(s, b.w, a.w);
}

// ---------------------------------------------------------------------------
// Kernel 1 "prep": Qt = PRESCALE*(Q@W_q), Kt = PRESCALE*(K@W_k), VW = V@W_o.
// grid 512 x 256 thr. Block = 16 output rows x 128 output cols.
//   [0,128): Qt   [128,256): Kt   [256,512): VW (row-block, col-half)
// Thread = 2 rows (r, r+8) x 4 cols -> 6 ds_read_b128 per 32 v_fma
// (vs 5 per 16 in R3: halves LDS traffic). LDS 48 KB.
// ---------------------------------------------------------------------------
__global__ __launch_bounds__(256) void prep_kernel(
    const float* __restrict__ Q, const float* __restrict__ K,
    const float* __restrict__ V,
    const float* __restrict__ Wq, const float* __restrict__ Wk,
    const float* __restrict__ Wo,
    float* __restrict__ Qt, float* __restrict__ Kt, float* __restrict__ VW)
{
    __shared__ float rows[16 * HH];    // 16 KB
    __shared__ float wl[64 * 128];     // 32 KB
    int tid = threadIdx.x;
    int bid = blockIdx.x;

    const float* X; const float* W; float* Y;
    int ldW, ldY, col0, r0; float scale;
    if (bid < 128)      { X=Q; W=Wq; Y=Qt; ldW=AA; ldY=AA; col0=0; r0=bid*16;       scale=PRESCALE; }
    else if (bid < 256) { X=K; W=Wk; Y=Kt; ldW=AA; ldY=AA; col0=0; r0=(bid-128)*16; scale=PRESCALE; }
    else { int b2=bid-256; X=V; W=Wo; Y=VW; ldW=HH; ldY=HH; col0=(b2&1)*128; r0=(b2>>1)*16; scale=1.0f; }

    // stage 16 input rows (4096 floats, contiguous, float4)
    {
        const float4* Xv = (const float4*)(X + (size_t)r0 * HH);
        float4* rv = (float4*)rows;
        rv[tid]       = Xv[tid];
        rv[tid + 256] = Xv[tid + 256];
        rv[tid + 512] = Xv[tid + 512];
        rv[tid + 768] = Xv[tid + 768];
    }

    int r  = tid >> 5;       // rows r and r+8
    int c4 = tid & 31;       // float4 output col
    float4 accA = {0.f,0.f,0.f,0.f}, accB = {0.f,0.f,0.f,0.f};

    for (int ch = 0; ch < 4; ++ch) {
        __syncthreads();     // rows staged / previous wl reads done
        {   // stage W rows [ch*64, ch*64+64) x cols [col0,col0+128): 2048 float4
            const float* Wbase = W + (size_t)(ch * 64) * ldW + col0;
            float4* wv = (float4*)wl;
            #pragma unroll
            for (int it = 0; it < 8; ++it) {
                int l = tid + it * 256;
                wv[l] = *(const float4*)(Wbase + (size_t)(l >> 5) * ldW + ((l & 31) << 2));
            }
        }
        __syncthreads();
        const float* rrowA = rows + r * HH + ch * 64;
        const float* rrowB = rows + (r + 8) * HH + ch * 64;
        #pragma unroll 4
        for (int h4 = 0; h4 < 16; ++h4) {
            float4 ra = *(const float4*)(rrowA + h4 * 4);       // broadcast b128
            float4 rb = *(const float4*)(rrowB + h4 * 4);       // broadcast b128
            const float* wbase = wl + (h4 * 4) * 128 + (c4 << 2);
            float4 w0 = *(const float4*)(wbase);                // contiguous b128
            float4 w1 = *(const float4*)(wbase + 128);
            float4 w2 = *(const float4*)(wbase + 256);
            float4 w3 = *(const float4*)(wbase + 384);
            fma4(accA, ra.x, w0); fma4(accA, ra.y, w1);
            fma4(accA, ra.z, w2); fma4(accA, ra.w, w3);
            fma4(accB, rb.x, w0); fma4(accB, rb.y, w1);
            fma4(accB, rb.z, w2); fma4(accB, rb.w, w3);
        }
    }
    accA.x *= scale; accA.y *= scale; accA.z *= scale; accA.w *= scale;
    accB.x *= scale; accB.y *= scale; accB.z *= scale; accB.w *= scale;
    *(float4*)(Y + (size_t)(r0 + r)     * ldY + col0 + (c4 << 2)) = accA;
    *(float4*)(Y + (size_t)(r0 + r + 8) * ldY + col0 + (c4 << 2)) = accB;
}

// ---------------------------------------------------------------------------
// Kernel 2: fused scores + softmax + (weights @ VW + b_o).
// grid = B*SQ/2 = 1024 blocks x 256 thr (exactly 4 blocks/CU co-resident).
//   score[q][k] = S_all - sum_a 2*v[a] * rcp(2^(Qt[q][a]+Kt[k][a]) + 1)
// NO Kt LDS tile: thread (ag=tid&7, kl=tid>>3) loads its private 64B slice
// Kt[k][16ag..16ag+16) straight from global (one fully-used cache line per
// lane, L1/L2-hot) -> zero bank conflicts, ZERO in-loop barriers.
// a-reduction over the 8 ag-lanes = 3 shfl_xor.
// Epilogue: wave w owns k-quarter; VW read ONCE per block; LDS tree-reduce.
// ---------------------------------------------------------------------------
__global__ __launch_bounds__(256) void score_kernel(
    const float* __restrict__ Qt, const float* __restrict__ Kt,
    const float* __restrict__ v,  const float* __restrict__ VW,
    const float* __restrict__ bo,
    float* __restrict__ weights,  float* __restrict__ out)
{
    __shared__ float score[2][SKL];      // 4 KB
    __shared__ float pout[4][2][HH];     // 8 KB   (total 12 KB)

    int tid = threadIdx.x;
    int b  = blockIdx.x >> 8;            // 256 blocks per batch
    int q0 = (blockIdx.x & 255) << 1;    // 2 q-rows per block
    int ag = tid & 7;                    // a-range [16ag, 16ag+16)
    int kl = tid >> 3;                   // k within 32-chunk

    // register caches: Qt fragments (prescaled) + 2*v fragment
    float qreg0[16], qreg1[16], v2reg[16];
    {
        const float4* vp  = (const float4*)(v + ag * 16);
        const float4* qp0 = (const float4*)(Qt + (size_t)(b * SQL + q0)     * AA + ag * 16);
        const float4* qp1 = (const float4*)(Qt + (size_t)(b * SQL + q0 + 1) * AA + ag * 16);
        #pragma unroll
        for (int j4 = 0; j4 < 4; ++j4) {
            float4 vv4 = vp[j4];
            *(float4*)&qreg0[j4 * 4] = qp0[j4];
            *(float4*)&qreg1[j4 * 4] = qp1[j4];
            v2reg[j4 * 4 + 0] = 2.0f * vv4.x;
            v2reg[j4 * 4 + 1] = 2.0f * vv4.y;
            v2reg[j4 * 4 + 2] = 2.0f * vv4.z;
            v2reg[j4 * 4 + 3] = 2.0f * vv4.w;
        }
    }

    // S_all = sum_a v[a]: local partial then xor-reduce over the 8 ag-lanes
    float S_all;
    {
        float ls = 0.f;
        #pragma unroll
        for (int j = 0; j < 16; ++j) ls += v2reg[j];
        ls += __shfl_xor(ls, 1);
        ls += __shfl_xor(ls, 2);
        ls += __shfl_xor(ls, 4);
        S_all = 0.5f * ls;               // ls = 2*sum(v)
    }

    // ---- main loop: 16 chunks x 32 k-rows, no barriers, no LDS ----
    for (int c = 0; c < 16; ++c) {
        int k = c * 32 + kl;
        const float4* kt4 = (const float4*)(Kt + (size_t)(b * SKL + k) * AA + ag * 16);
        float kt[16];
        *(float4*)&kt[0]  = kt4[0];
        *(float4*)&kt[4]  = kt4[1];
        *(float4*)&kt[8]  = kt4[2];
        *(float4*)&kt[12] = kt4[3];

        float p0 = 0.f, p1 = 0.f;
        #pragma unroll
        for (int j = 0; j < 16; ++j) {
            float kv = kt[j];
            float x0 = qreg0[j] + kv;
            float x1 = qreg1[j] + kv;
            float e0 = __builtin_amdgcn_exp2f(x0);
            float e1 = __builtin_amdgcn_exp2f(x1);
            float r0 = __builtin_amdgcn_rcpf(e0 + 1.0f);
            float r1 = __builtin_amdgcn_rcpf(e1 + 1.0f);
            p0 = fmaf(v2reg[j], r0, p0);
            p1 = fmaf(v2reg[j], r1, p1);
        }
        // reduce over 8 ag-lanes (adjacent in tid)
        p0 += __shfl_xor(p0, 1); p1 += __shfl_xor(p1, 1);
        p0 += __shfl_xor(p0, 2); p1 += __shfl_xor(p1, 2);
        p0 += __shfl_xor(p0, 4); p1 += __shfl_xor(p1, 4);
        if (ag == 0) {
            score[0][k] = S_all - p0;
            score[1][k] = S_all - p1;
        }
    }
    __syncthreads();

    // ---- softmax: wave 0 -> row 0, wave 1 -> row 1
    int wave = tid >> 6, lane = tid & 63;
    if (wave < 2) {
        int qi = wave;
        float m = -1e30f;
        for (int k = lane; k < SKL; k += 64) m = fmaxf(m, score[qi][k]);
        #pragma unroll
        for (int off = 32; off; off >>= 1) m = fmaxf(m, __shfl_xor(m, off));
        float s = 0.f;
        for (int k = lane; k < SKL; k += 64) {
            float e = __builtin_amdgcn_exp2f((score[qi][k] - m) * 1.44269504f);
            score[qi][k] = e;
            s += e;
        }
        #pragma unroll
        for (int off = 32; off; off >>= 1) s += __shfl_xor(s, off);
        float rinv = 1.0f / s;
        size_t rowoff = (size_t)(b * SQL + q0 + qi) * SKL;
        for (int k = lane; k < SKL; k += 64) {
            float wv2 = score[qi][k] * rinv;
            score[qi][k] = wv2;
            weights[rowoff + k] = wv2;
        }
    }
    __syncthreads();

    // ---- epilogue: wave w owns k in [128w, 128w+128); one VW read serves both q
    {
        const float4* VWb = (const float4*)(VW + (size_t)b * SKL * HH);
        float4 a0 = {0,0,0,0}, a1 = {0,0,0,0};
        int kbase = wave * 128;
        #pragma unroll 4
        for (int k = 0; k < 128; ++k) {
            int kk = kbase + k;
            float4 vw4 = VWb[kk * (HH / 4) + lane];   // coalesced dwordx4
            float w0 = score[0][kk];                  // wave-uniform broadcast
            float w1 = score[1][kk];
            fma4(a0, w0, vw4);
            fma4(a1, w1, vw4);
        }
        *(float4*)&pout[wave][0][lane << 2] = a0;
        *(float4*)&pout[wave][1][lane << 2] = a1;
    }
    __syncthreads();
    {
        int h = tid;
        float bias = bo[h];
        #pragma unroll
        for (int qi = 0; qi < 2; ++qi) {
            float s = bias + pout[0][qi][h] + pout[1][qi][h]
                           + pout[2][qi][h] + pout[3][qi][h];
            out[(size_t)(b * SQL + q0 + qi) * HH + h] = s;
        }
    }
}

// ---------------------------------------------------------------------------
extern "C" void kernel_launch(void* const* d_in, const int* in_sizes, int n_in,
                              void* d_out, int out_size, void* d_ws, size_t ws_size,
                              hipStream_t stream)
{
    const float* Q  = (const float*)d_in[0];
    const float* K  = (const float*)d_in[1];
    const float* V  = (const float*)d_in[2];
    const float* Wq = (const float*)d_in[3];
    const float* Wk = (const float*)d_in[4];
    const float* v  = (const float*)d_in[5];
    const float* Wo = (const float*)d_in[6];
    const float* bo = (const float*)d_in[7];

    float* out     = (float*)d_out;                   // (B,SQ,H) = 524288
    float* weights = out + (size_t)BB * SQL * HH;     // (B,SQ,SK) = 1048576

    float* Qt = (float*)d_ws;                         // 262144 floats
    float* Kt = Qt + (size_t)BB * SQL * AA;           // 262144 floats
    float* VW = Kt + (size_t)BB * SKL * AA;           // 524288 floats

    prep_kernel <<<512, 256, 0, stream>>>(Q, K, V, Wq, Wk, Wo, Qt, Kt, VW);
    score_kernel<<<1024, 256, 0, stream>>>(Qt, Kt, v, VW, bo, weights, out);
}